// Round 4
// baseline (605.431 us; speedup 1.0000x reference)
//
#include <hip/hip_runtime.h>
#include <hip/hip_bf16.h>

#define N_NODES 40000
#define IN_DIM 256
#define OUT_DIM 128

__device__ __forceinline__ int clamp_idx(int v) {
    unsigned u = (unsigned)v;
    return (u < (unsigned)N_NODES) ? v : 0;
}

// Unified index accessor: edge_index may be int32 or int64 on device.
__device__ __forceinline__ int get_idx(const void* p, long long i, int is64) {
    if (is64) return clamp_idx((int)((const long long*)p)[i]);
    return clamp_idx(((const int*)p)[i]);
}

// ---- dtype detector: int64 (values < 2^31) has zero high-halves at odd slots ----
__global__ void detect_r4(const int* __restrict__ edge32, int* __restrict__ flag) {
    if (threadIdx.x == 0 && blockIdx.x == 0) {
        int nonzero = 0;
        for (int i = 1; i < 2001; i += 2) nonzero |= (edge32[i] != 0);
        *flag = nonzero ? 0 : 1;   // 1 => int64
    }
}

// ---------------- init: zero agg, deg=1 (self-loop) ----------------
__global__ void init_r4(float* __restrict__ agg, int* __restrict__ deg, int aggN) {
    int i = blockIdx.x * blockDim.x + threadIdx.x;
    if (i < aggN) agg[i] = 0.0f;
    if (i < N_NODES) deg[i] = 1;
}

// ---------------- degree count over dst ----------------
__global__ void deg_r4(const void* __restrict__ edge, int* __restrict__ deg, int E,
                       const int* __restrict__ flag) {
    int is64 = *flag;
    int e = blockIdx.x * blockDim.x + threadIdx.x;
    if (e < E) atomicAdd(&deg[get_idx(edge, (long long)E + e, is64)], 1);
}

// ---------------- dinv = rsqrt(deg) ----------------
__global__ void dinv_r4(const int* __restrict__ deg, float* __restrict__ dinv) {
    int i = blockIdx.x * blockDim.x + threadIdx.x;
    if (i < N_NODES) {
        int d = deg[i];
        dinv[i] = (d > 0) ? rsqrtf((float)d) : 0.0f;
    }
}

// ---------------- xw = x @ W  (one block of 128 threads per row) ----------------
__global__ void gemm_r4(const float* __restrict__ x,
                        const float* __restrict__ W,
                        float* __restrict__ xw) {
    int m = blockIdx.x;
    int n = threadIdx.x;  // 0..127
    __shared__ float xs[IN_DIM];
    xs[n]       = x[m * IN_DIM + n];
    xs[n + 128] = x[m * IN_DIM + n + 128];
    __syncthreads();
    float acc = 0.0f;
#pragma unroll 8
    for (int k = 0; k < IN_DIM; ++k)
        acc += xs[k] * W[k * OUT_DIM + n];
    xw[m * OUT_DIM + n] = acc;
}

// ---------------- edge scatter: agg[dst] += norm * xw[src] ----------------
// 256 threads = 2 edges x 128 channels
__global__ void scatter_r4(const void* __restrict__ edge,
                           const float* __restrict__ dinv, const float* __restrict__ xw,
                           float* __restrict__ agg, int E,
                           const int* __restrict__ flag) {
    int is64 = *flag;
    int e = blockIdx.x * 2 + (threadIdx.x >> 7);
    int c = threadIdx.x & (OUT_DIM - 1);
    if (e >= E) return;
    int s = get_idx(edge, e, is64);
    int d = get_idx(edge, (long long)E + e, is64);
    float norm = dinv[s] * dinv[d];
    atomicAdd(&agg[d * OUT_DIM + c], norm * xw[s * OUT_DIM + c]);
}

// ---------------- epilogue: self-loop + bias + relu -> fp32 out ----------------
__global__ void final_r4(const float* __restrict__ agg, const float* __restrict__ xw,
                         const float* __restrict__ dinv, const float* __restrict__ b,
                         float* __restrict__ out, int total) {
    int i = blockIdx.x * blockDim.x + threadIdx.x;
    if (i >= total) return;
    int node = i >> 7;          // /128
    int c = i & (OUT_DIM - 1);
    float di = dinv[node];
    float v = agg[i] + di * di * xw[i] + b[c];
    out[i] = fmaxf(v, 0.0f);
}

extern "C" void kernel_launch(void* const* d_in, const int* in_sizes, int n_in,
                              void* d_out, int out_size, void* d_ws, size_t ws_size,
                              hipStream_t stream) {
    const float* x  = (const float*)d_in[0];
    const void* edge = d_in[1];                 // int32 or int64, detected on device
    const float* W  = (const float*)d_in[2];
    const float* b  = (const float*)d_in[3];
    float* out      = (float*)d_out;            // fp32 output per reference dtype

    const int E = in_sizes[1] / 2;              // 640000

    char* ws = (char*)d_ws;
    // layout: deg 160000 | dinv 160000 | flag 256 | xw 20480000 | agg 20480000
    int*   deg  = (int*)(ws);
    float* dinv = (float*)(ws + 160000);
    int*   flag = (int*)(ws + 320000);
    float* xw   = (float*)(ws + 320256);
    float* agg  = (float*)(ws + 20800256);

    const int total = N_NODES * OUT_DIM;        // 5120000

    detect_r4<<<1, 64, 0, stream>>>((const int*)edge, flag);
    init_r4<<<(total + 255) / 256, 256, 0, stream>>>(agg, deg, total);
    deg_r4<<<(E + 255) / 256, 256, 0, stream>>>(edge, deg, E, flag);
    dinv_r4<<<(N_NODES + 255) / 256, 256, 0, stream>>>(deg, dinv);
    gemm_r4<<<N_NODES, 128, 0, stream>>>(x, W, xw);
    scatter_r4<<<(E + 1) / 2, 256, 0, stream>>>(edge, dinv, xw, agg, E, flag);
    final_r4<<<(total + 255) / 256, 256, 0, stream>>>(agg, xw, dinv, b, out, total);
}

// Round 5
// 400.643 us; speedup vs baseline: 1.5111x; 1.5111x over previous
//
#include <hip/hip_runtime.h>

#define N_NODES 40000
#define IN_DIM 256
#define OUT_DIM 128

__device__ __forceinline__ int clamp_idx(int v) {
    unsigned u = (unsigned)v;
    return (u < (unsigned)N_NODES) ? v : 0;
}

// Unified index accessor: edge_index may be int32 or int64 on device.
__device__ __forceinline__ int get_idx(const void* p, long long i, int is64) {
    if (is64) return clamp_idx((int)((const long long*)p)[i]);
    return clamp_idx(((const int*)p)[i]);
}

// ---- dtype detector: int64 (values < 2^31) has zero high-halves at odd slots ----
__global__ void detect_r5(const int* __restrict__ edge32, int* __restrict__ flag) {
    if (threadIdx.x == 0 && blockIdx.x == 0) {
        int nonzero = 0;
        for (int i = 1; i < 2001; i += 2) nonzero |= (edge32[i] != 0);
        *flag = nonzero ? 0 : 1;   // 1 => int64
    }
}

// ---------------- deg = 1 (self-loop) ----------------
__global__ void initdeg_r5(int* __restrict__ deg) {
    int i = blockIdx.x * blockDim.x + threadIdx.x;
    if (i < N_NODES) deg[i] = 1;
}

// ---------------- degree count over dst ----------------
__global__ void deg_r5(const void* __restrict__ edge, int* __restrict__ deg, int E,
                       const int* __restrict__ flag) {
    int is64 = *flag;
    int e = blockIdx.x * blockDim.x + threadIdx.x;
    if (e < E) atomicAdd(&deg[get_idx(edge, (long long)E + e, is64)], 1);
}

// ---------------- dinv = rsqrt(deg) ----------------
__global__ void dinv_r5(const int* __restrict__ deg, float* __restrict__ dinv) {
    int i = blockIdx.x * blockDim.x + threadIdx.x;
    if (i < N_NODES) dinv[i] = rsqrtf((float)deg[i]);   // deg >= 1 always
}

// ---------------- exclusive scan of (deg-1): CSR offsets ----------------
// single block, 1024 threads x 40 elements
__global__ void scan_r5(const int* __restrict__ deg, int* __restrict__ offs,
                        int* __restrict__ cursor) {
    const int T = 1024, CH = 40;
    __shared__ int part[T];
    int t = threadIdx.x;
    int base = t * CH;
    int cnt[CH];
    int sum = 0;
#pragma unroll
    for (int j = 0; j < CH; ++j) {
        int i = base + j;
        int c = (i < N_NODES) ? (deg[i] - 1) : 0;
        cnt[j] = c; sum += c;
    }
    part[t] = sum;
    __syncthreads();
    for (int off = 1; off < T; off <<= 1) {
        int v = (t >= off) ? part[t - off] : 0;
        __syncthreads();
        part[t] += v;
        __syncthreads();
    }
    int run = part[t] - sum;  // exclusive prefix
#pragma unroll
    for (int j = 0; j < CH; ++j) {
        int i = base + j;
        if (i < N_NODES) { offs[i] = run; cursor[i] = run; }
        run += cnt[j];
    }
}

// ---------------- CSR fill: bucket src by dst ----------------
__global__ void fill_r5(const void* __restrict__ edge, int* __restrict__ cursor,
                        int* __restrict__ csr_src, int E, const int* __restrict__ flag) {
    int is64 = *flag;
    int e = blockIdx.x * blockDim.x + threadIdx.x;
    if (e >= E) return;
    int s = get_idx(edge, e, is64);
    int d = get_idx(edge, (long long)E + e, is64);
    int pos = atomicAdd(&cursor[d], 1);
    csr_src[pos] = s;
}

// ---------------- xw = x @ W : 16 rows/block, 8 rows x 1 col per thread ------
#define ROWS 16
__global__ void gemm_r5(const float* __restrict__ x, const float* __restrict__ W,
                        float* __restrict__ xw) {
    // x tile transposed in LDS, k-major, row padded to 20 floats (16B-aligned r0, banks spread)
    __shared__ float xsT[IN_DIM * 20];
    int t = threadIdx.x;
    int m0 = blockIdx.x * ROWS;
    for (int idx = t; idx < ROWS * IN_DIM; idx += 256) {
        int r = idx >> 8;          // 0..15
        int k = idx & 255;
        xsT[k * 20 + r] = x[(m0 + r) * IN_DIM + k];
    }
    __syncthreads();
    int n  = t & 127;
    int r0 = (t >> 7) * 8;         // 0 or 8
    float acc[8] = {0, 0, 0, 0, 0, 0, 0, 0};
#pragma unroll 4
    for (int k = 0; k < IN_DIM; ++k) {
        float w = W[k * OUT_DIM + n];                    // coalesced, L2-hot (128 KB)
        const float4* p = (const float4*)&xsT[k * 20 + r0];
        float4 a = p[0];                                 // broadcast within wave
        float4 c = p[1];
        acc[0] += a.x * w; acc[1] += a.y * w; acc[2] += a.z * w; acc[3] += a.w * w;
        acc[4] += c.x * w; acc[5] += c.y * w; acc[6] += c.z * w; acc[7] += c.w * w;
    }
#pragma unroll
    for (int j = 0; j < 8; ++j)
        xw[(m0 + r0 + j) * OUT_DIM + n] = acc[j];
}

// ---------------- gather: one wave per node, fused self-loop+bias+relu ------
__global__ void gather_r5(const int* __restrict__ csr_src, const int* __restrict__ offs,
                          const int* __restrict__ deg, const float* __restrict__ dinv,
                          const float* __restrict__ xw, const float* __restrict__ b,
                          float* __restrict__ out) {
    int node = blockIdx.x * 4 + (threadIdx.x >> 6);
    int lane = threadIdx.x & 63;
    if (node >= N_NODES) return;
    float dd  = dinv[node];
    float dd2 = dd * dd;
    float a0 = dd2 * xw[node * OUT_DIM + lane];          // self-loop term
    float a1 = dd2 * xw[node * OUT_DIM + 64 + lane];
    int beg = offs[node];
    int cnt = deg[node] - 1;                             // real in-edges
    for (int j = 0; j < cnt; ++j) {
        int s = csr_src[beg + j];                        // same addr all lanes: broadcast
        float nrm = dd * dinv[s];
        a0 += nrm * xw[s * OUT_DIM + lane];
        a1 += nrm * xw[s * OUT_DIM + 64 + lane];
    }
    out[node * OUT_DIM + lane]      = fmaxf(a0 + b[lane], 0.0f);
    out[node * OUT_DIM + 64 + lane] = fmaxf(a1 + b[64 + lane], 0.0f);
}

extern "C" void kernel_launch(void* const* d_in, const int* in_sizes, int n_in,
                              void* d_out, int out_size, void* d_ws, size_t ws_size,
                              hipStream_t stream) {
    const float* x   = (const float*)d_in[0];
    const void* edge = d_in[1];                 // int32 or int64, detected on device
    const float* W   = (const float*)d_in[2];
    const float* b   = (const float*)d_in[3];
    float* out       = (float*)d_out;           // fp32 output

    const int E = in_sizes[1] / 2;              // 640000

    char* ws = (char*)d_ws;
    // layout: deg 160000 | dinv 160000 | flag 256 | offs 160000 | cursor 160000
    //         | csr_src 2560000 | xw 20480000   (total ~23.7 MB)
    int*   deg     = (int*)(ws);
    float* dinv    = (float*)(ws + 160000);
    int*   flag    = (int*)(ws + 320000);
    int*   offs    = (int*)(ws + 320256);
    int*   cursor  = (int*)(ws + 480256);
    int*   csr_src = (int*)(ws + 640256);
    float* xw      = (float*)(ws + 3200256);

    detect_r5<<<1, 64, 0, stream>>>((const int*)edge, flag);
    initdeg_r5<<<(N_NODES + 255) / 256, 256, 0, stream>>>(deg);
    deg_r5<<<(E + 255) / 256, 256, 0, stream>>>(edge, deg, E, flag);
    dinv_r5<<<(N_NODES + 255) / 256, 256, 0, stream>>>(deg, dinv);
    scan_r5<<<1, 1024, 0, stream>>>(deg, offs, cursor);
    fill_r5<<<(E + 255) / 256, 256, 0, stream>>>(edge, cursor, csr_src, E, flag);
    gemm_r5<<<N_NODES / ROWS, 256, 0, stream>>>(x, W, xw);
    gather_r5<<<N_NODES / 4, 256, 0, stream>>>(csr_src, offs, deg, dinv, xw, b, out);
}

// Round 6
// 347.000 us; speedup vs baseline: 1.7448x; 1.1546x over previous
//
#include <hip/hip_runtime.h>

#define N_NODES 40000
#define IN_DIM 256
#define OUT_DIM 128

__device__ __forceinline__ int clamp_idx(int v) {
    unsigned u = (unsigned)v;
    return (u < (unsigned)N_NODES) ? v : 0;
}

__device__ __forceinline__ int get_idx(const void* p, long long i, int is64) {
    if (is64) return clamp_idx((int)((const long long*)p)[i]);
    return clamp_idx(((const int*)p)[i]);
}

// ---- fused: parallel dtype detect (block 0) + deg=1 init (all blocks) ----
__global__ void detinit_r6(const int* __restrict__ edge32, int* __restrict__ flag,
                           int* __restrict__ deg) {
    int i = blockIdx.x * blockDim.x + threadIdx.x;
    if (i < N_NODES) deg[i] = 1;
    if (blockIdx.x == 0) {
        __shared__ int nzs;
        if (threadIdx.x == 0) nzs = 0;
        __syncthreads();
        int nz = 0;
        for (int k = threadIdx.x; k < 1000; k += 256) nz |= (edge32[2 * k + 1] != 0);
        if (nz) atomicOr(&nzs, 1);
        __syncthreads();
        if (threadIdx.x == 0) *flag = nzs ? 0 : 1;   // 1 => int64
    }
}

// ---------------- degree count over dst ----------------
__global__ void deg_r6(const void* __restrict__ edge, int* __restrict__ deg, int E,
                       const int* __restrict__ flag) {
    int is64 = *flag;
    int e = blockIdx.x * blockDim.x + threadIdx.x;
    if (e < E) atomicAdd(&deg[get_idx(edge, (long long)E + e, is64)], 1);
}

// ------- exclusive scan of (deg-1) + fused dinv: single block, 1024 x 40 -------
__global__ void scan_r6(const int* __restrict__ deg, int* __restrict__ offs,
                        int* __restrict__ cursor, float* __restrict__ dinv) {
    const int T = 1024, CH = 40;
    __shared__ int part[T];
    int t = threadIdx.x;
    int base = t * CH;
    int cnt[CH];
    int sum = 0;
#pragma unroll
    for (int j = 0; j < CH; ++j) {
        int i = base + j;
        int dg = (i < N_NODES) ? deg[i] : 1;
        if (i < N_NODES) dinv[i] = rsqrtf((float)dg);
        int c = dg - 1;
        cnt[j] = c; sum += c;
    }
    part[t] = sum;
    __syncthreads();
    for (int off = 1; off < T; off <<= 1) {
        int v = (t >= off) ? part[t - off] : 0;
        __syncthreads();
        part[t] += v;
        __syncthreads();
    }
    int run = part[t] - sum;  // exclusive prefix
#pragma unroll
    for (int j = 0; j < CH; ++j) {
        int i = base + j;
        if (i < N_NODES) { offs[i] = run; cursor[i] = run; }
        run += cnt[j];
    }
}

// ---------------- CSR fill: bucket src by dst ----------------
__global__ void fill_r6(const void* __restrict__ edge, int* __restrict__ cursor,
                        int* __restrict__ csr_src, int E, const int* __restrict__ flag) {
    int is64 = *flag;
    int e = blockIdx.x * blockDim.x + threadIdx.x;
    if (e >= E) return;
    int s = get_idx(edge, e, is64);
    int d = get_idx(edge, (long long)E + e, is64);
    int pos = atomicAdd(&cursor[d], 1);
    csr_src[pos] = s;
}

// ---------------- xw = x @ W : 16 rows/block, 8 rows x 1 col per thread ------
#define ROWS 16
__global__ void gemm_r6(const float* __restrict__ x, const float* __restrict__ W,
                        float* __restrict__ xw) {
    __shared__ float xsT[IN_DIM * 20];
    int t = threadIdx.x;
    int m0 = blockIdx.x * ROWS;
    for (int idx = t; idx < ROWS * IN_DIM; idx += 256) {
        int r = idx >> 8;
        int k = idx & 255;
        xsT[k * 20 + r] = x[(m0 + r) * IN_DIM + k];
    }
    __syncthreads();
    int n  = t & 127;
    int r0 = (t >> 7) * 8;
    float acc[8] = {0, 0, 0, 0, 0, 0, 0, 0};
#pragma unroll 4
    for (int k = 0; k < IN_DIM; ++k) {
        float w = W[k * OUT_DIM + n];
        const float4* p = (const float4*)&xsT[k * 20 + r0];
        float4 a = p[0];
        float4 c = p[1];
        acc[0] += a.x * w; acc[1] += a.y * w; acc[2] += a.z * w; acc[3] += a.w * w;
        acc[4] += c.x * w; acc[5] += c.y * w; acc[6] += c.z * w; acc[7] += c.w * w;
    }
#pragma unroll
    for (int j = 0; j < 8; ++j)
        xw[(m0 + r0 + j) * OUT_DIM + n] = acc[j];
}

// ------- gather v2: one wave per node, chunked coalesced idx load + shfl ------
__global__ void gather_r6(const int* __restrict__ csr_src, const int* __restrict__ offs,
                          const int* __restrict__ deg, const float* __restrict__ dinv,
                          const float* __restrict__ xw, const float* __restrict__ b,
                          float* __restrict__ out) {
    int node = blockIdx.x * 4 + (threadIdx.x >> 6);
    int lane = threadIdx.x & 63;
    if (node >= N_NODES) return;
    float dd = dinv[node];
    float a0 = dd * dd * xw[node * OUT_DIM + lane];
    float a1 = dd * dd * xw[node * OUT_DIM + 64 + lane];
    int beg = offs[node];
    int cnt = deg[node] - 1;
    for (int c0 = 0; c0 < cnt; c0 += 64) {
        int rem = cnt - c0;
        int take = rem < 64 ? rem : 64;
        int s_l = 0; float nrm_l = 0.0f;
        if (lane < take) {
            s_l = csr_src[beg + c0 + lane];     // coalesced
            nrm_l = dd * dinv[s_l];
        }
        int j = 0;
        for (; j + 4 <= take; j += 4) {
            int   s0 = __shfl(s_l, j),     s1 = __shfl(s_l, j + 1);
            int   s2 = __shfl(s_l, j + 2), s3 = __shfl(s_l, j + 3);
            float n0 = __shfl(nrm_l, j),     n1 = __shfl(nrm_l, j + 1);
            float n2 = __shfl(nrm_l, j + 2), n3 = __shfl(nrm_l, j + 3);
            // 8 independent row loads in flight
            float x00 = xw[s0 * OUT_DIM + lane], x01 = xw[s0 * OUT_DIM + 64 + lane];
            float x10 = xw[s1 * OUT_DIM + lane], x11 = xw[s1 * OUT_DIM + 64 + lane];
            float x20 = xw[s2 * OUT_DIM + lane], x21 = xw[s2 * OUT_DIM + 64 + lane];
            float x30 = xw[s3 * OUT_DIM + lane], x31 = xw[s3 * OUT_DIM + 64 + lane];
            a0 += n0 * x00; a1 += n0 * x01;
            a0 += n1 * x10; a1 += n1 * x11;
            a0 += n2 * x20; a1 += n2 * x21;
            a0 += n3 * x30; a1 += n3 * x31;
        }
        for (; j < take; ++j) {
            int   s = __shfl(s_l, j);
            float n = __shfl(nrm_l, j);
            a0 += n * xw[s * OUT_DIM + lane];
            a1 += n * xw[s * OUT_DIM + 64 + lane];
        }
    }
    out[node * OUT_DIM + lane]      = fmaxf(a0 + b[lane], 0.0f);
    out[node * OUT_DIM + 64 + lane] = fmaxf(a1 + b[64 + lane], 0.0f);
}

extern "C" void kernel_launch(void* const* d_in, const int* in_sizes, int n_in,
                              void* d_out, int out_size, void* d_ws, size_t ws_size,
                              hipStream_t stream) {
    const float* x   = (const float*)d_in[0];
    const void* edge = d_in[1];                 // int32 or int64, detected on device
    const float* W   = (const float*)d_in[2];
    const float* b   = (const float*)d_in[3];
    float* out       = (float*)d_out;           // fp32 output

    const int E = in_sizes[1] / 2;              // 640000

    char* ws = (char*)d_ws;
    // layout: deg 160000 | dinv 160000 | flag 256 | offs 160000 | cursor 160000
    //         | csr_src 2560000 | xw 20480000   (total ~23.7 MB)
    int*   deg     = (int*)(ws);
    float* dinv    = (float*)(ws + 160000);
    int*   flag    = (int*)(ws + 320000);
    int*   offs    = (int*)(ws + 320256);
    int*   cursor  = (int*)(ws + 480256);
    int*   csr_src = (int*)(ws + 640256);
    float* xw      = (float*)(ws + 3200256);

    detinit_r6<<<(N_NODES + 255) / 256, 256, 0, stream>>>((const int*)edge, flag, deg);
    deg_r6<<<(E + 255) / 256, 256, 0, stream>>>(edge, deg, E, flag);
    scan_r6<<<1, 1024, 0, stream>>>(deg, offs, cursor, dinv);
    fill_r6<<<(E + 255) / 256, 256, 0, stream>>>(edge, cursor, csr_src, E, flag);
    gemm_r6<<<N_NODES / ROWS, 256, 0, stream>>>(x, W, xw);
    gather_r6<<<N_NODES / 4, 256, 0, stream>>>(csr_src, offs, deg, dinv, xw, b, out);
}

// Round 7
// 263.326 us; speedup vs baseline: 2.2992x; 1.3178x over previous
//
#include <hip/hip_runtime.h>

#define N_NODES 40000
#define IN_DIM 256
#define OUT_DIM 128
#define SCAN_BLOCKS ((N_NODES + 255) / 256)   // 157

__device__ __forceinline__ int clamp_idx(int v) {
    unsigned u = (unsigned)v;
    return (u < (unsigned)N_NODES) ? v : 0;
}

__device__ __forceinline__ int get_idx(const void* p, long long i, int is64) {
    if (is64) return clamp_idx((int)((const long long*)p)[i]);
    return clamp_idx(((const int*)p)[i]);
}

// ---- fused: parallel dtype detect (block 0) + deg=1 init (all blocks) ----
__global__ void detinit_r7(const int* __restrict__ edge32, int* __restrict__ flag,
                           int* __restrict__ deg) {
    int i = blockIdx.x * blockDim.x + threadIdx.x;
    if (i < N_NODES) deg[i] = 1;
    if (blockIdx.x == 0) {
        __shared__ int nzs;
        if (threadIdx.x == 0) nzs = 0;
        __syncthreads();
        int nz = 0;
        for (int k = threadIdx.x; k < 1000; k += 256) nz |= (edge32[2 * k + 1] != 0);
        if (nz) atomicOr(&nzs, 1);
        __syncthreads();
        if (threadIdx.x == 0) *flag = nzs ? 0 : 1;   // 1 => int64
    }
}

// ---------------- degree count over dst ----------------
__global__ void deg_r7(const void* __restrict__ edge, int* __restrict__ deg, int E,
                       const int* __restrict__ flag) {
    int is64 = *flag;
    int e = blockIdx.x * blockDim.x + threadIdx.x;
    if (e < E) atomicAdd(&deg[get_idx(edge, (long long)E + e, is64)], 1);
}

// ---------------- hierarchical scan, stage 1: per-block sums ----------------
__global__ void partial_r7(const int* __restrict__ deg, int* __restrict__ bsum) {
    __shared__ int sh[256];
    int t = threadIdx.x;
    int i = blockIdx.x * 256 + t;
    int v = (i < N_NODES) ? (deg[i] - 1) : 0;
    sh[t] = v;
    __syncthreads();
    for (int off = 128; off > 0; off >>= 1) {
        if (t < off) sh[t] += sh[t + off];
        __syncthreads();
    }
    if (t == 0) bsum[blockIdx.x] = sh[0];
}

// ---------------- stage 2: exclusive scan of block sums (1 block) ----------------
__global__ void scanblk_r7(const int* __restrict__ bsum, int* __restrict__ bscan) {
    __shared__ int sh[256];
    int t = threadIdx.x;
    int v = (t < SCAN_BLOCKS) ? bsum[t] : 0;
    sh[t] = v;
    __syncthreads();
    for (int off = 1; off < 256; off <<= 1) {
        int u = (t >= off) ? sh[t - off] : 0;
        __syncthreads();
        sh[t] += u;
        __syncthreads();
    }
    if (t < SCAN_BLOCKS) bscan[t] = sh[t] - v;   // exclusive
}

// ---- stage 3: within-block exclusive scan + base; fused dinv ----
__global__ void offs_r7(const int* __restrict__ deg, const int* __restrict__ bscan,
                        int* __restrict__ offs, int* __restrict__ cursor,
                        float* __restrict__ dinv) {
    __shared__ int sh[256];
    int t = threadIdx.x;
    int i = blockIdx.x * 256 + t;
    int dg = (i < N_NODES) ? deg[i] : 1;
    if (i < N_NODES) dinv[i] = rsqrtf((float)dg);
    int v = dg - 1;
    sh[t] = v;
    __syncthreads();
    for (int off = 1; off < 256; off <<= 1) {
        int u = (t >= off) ? sh[t - off] : 0;
        __syncthreads();
        sh[t] += u;
        __syncthreads();
    }
    if (i < N_NODES) {
        int o = bscan[blockIdx.x] + sh[t] - v;
        offs[i] = o;
        cursor[i] = o;
    }
}

// ---------------- CSR fill: bucket src by dst ----------------
__global__ void fill_r7(const void* __restrict__ edge, int* __restrict__ cursor,
                        int* __restrict__ csr_src, int E, const int* __restrict__ flag) {
    int is64 = *flag;
    int e = blockIdx.x * blockDim.x + threadIdx.x;
    if (e >= E) return;
    int s = get_idx(edge, e, is64);
    int d = get_idx(edge, (long long)E + e, is64);
    int pos = atomicAdd(&cursor[d], 1);
    csr_src[pos] = s;
}

// ---------------- xw = x @ W : 16 rows/block, 8 rows x 1 col per thread ------
#define ROWS 16
__global__ void gemm_r7(const float* __restrict__ x, const float* __restrict__ W,
                        float* __restrict__ xw) {
    __shared__ float xsT[IN_DIM * 20];
    int t = threadIdx.x;
    int m0 = blockIdx.x * ROWS;
    for (int idx = t; idx < ROWS * IN_DIM; idx += 256) {
        int r = idx >> 8;
        int k = idx & 255;
        xsT[k * 20 + r] = x[(m0 + r) * IN_DIM + k];
    }
    __syncthreads();
    int n  = t & 127;
    int r0 = (t >> 7) * 8;
    float acc[8] = {0, 0, 0, 0, 0, 0, 0, 0};
#pragma unroll 4
    for (int k = 0; k < IN_DIM; ++k) {
        float w = W[k * OUT_DIM + n];
        const float4* p = (const float4*)&xsT[k * 20 + r0];
        float4 a = p[0];
        float4 c = p[1];
        acc[0] += a.x * w; acc[1] += a.y * w; acc[2] += a.z * w; acc[3] += a.w * w;
        acc[4] += c.x * w; acc[5] += c.y * w; acc[6] += c.z * w; acc[7] += c.w * w;
    }
#pragma unroll
    for (int j = 0; j < 8; ++j)
        xw[(m0 + r0 + j) * OUT_DIM + n] = acc[j];
}

// ------- gather: one wave per node, chunked coalesced idx load + shfl ------
__global__ void gather_r7(const int* __restrict__ csr_src, const int* __restrict__ offs,
                          const int* __restrict__ deg, const float* __restrict__ dinv,
                          const float* __restrict__ xw, const float* __restrict__ b,
                          float* __restrict__ out) {
    int node = blockIdx.x * 4 + (threadIdx.x >> 6);
    int lane = threadIdx.x & 63;
    if (node >= N_NODES) return;
    float dd = dinv[node];
    float a0 = dd * dd * xw[node * OUT_DIM + lane];
    float a1 = dd * dd * xw[node * OUT_DIM + 64 + lane];
    int beg = offs[node];
    int cnt = deg[node] - 1;
    for (int c0 = 0; c0 < cnt; c0 += 64) {
        int rem = cnt - c0;
        int take = rem < 64 ? rem : 64;
        int s_l = 0; float nrm_l = 0.0f;
        if (lane < take) {
            s_l = csr_src[beg + c0 + lane];     // coalesced
            nrm_l = dd * dinv[s_l];
        }
        int j = 0;
        for (; j + 4 <= take; j += 4) {
            int   s0 = __shfl(s_l, j),     s1 = __shfl(s_l, j + 1);
            int   s2 = __shfl(s_l, j + 2), s3 = __shfl(s_l, j + 3);
            float n0 = __shfl(nrm_l, j),     n1 = __shfl(nrm_l, j + 1);
            float n2 = __shfl(nrm_l, j + 2), n3 = __shfl(nrm_l, j + 3);
            float x00 = xw[s0 * OUT_DIM + lane], x01 = xw[s0 * OUT_DIM + 64 + lane];
            float x10 = xw[s1 * OUT_DIM + lane], x11 = xw[s1 * OUT_DIM + 64 + lane];
            float x20 = xw[s2 * OUT_DIM + lane], x21 = xw[s2 * OUT_DIM + 64 + lane];
            float x30 = xw[s3 * OUT_DIM + lane], x31 = xw[s3 * OUT_DIM + 64 + lane];
            a0 += n0 * x00; a1 += n0 * x01;
            a0 += n1 * x10; a1 += n1 * x11;
            a0 += n2 * x20; a1 += n2 * x21;
            a0 += n3 * x30; a1 += n3 * x31;
        }
        for (; j < take; ++j) {
            int   s = __shfl(s_l, j);
            float n = __shfl(nrm_l, j);
            a0 += n * xw[s * OUT_DIM + lane];
            a1 += n * xw[s * OUT_DIM + 64 + lane];
        }
    }
    out[node * OUT_DIM + lane]      = fmaxf(a0 + b[lane], 0.0f);
    out[node * OUT_DIM + 64 + lane] = fmaxf(a1 + b[64 + lane], 0.0f);
}

extern "C" void kernel_launch(void* const* d_in, const int* in_sizes, int n_in,
                              void* d_out, int out_size, void* d_ws, size_t ws_size,
                              hipStream_t stream) {
    const float* x   = (const float*)d_in[0];
    const void* edge = d_in[1];                 // int32 or int64, detected on device
    const float* W   = (const float*)d_in[2];
    const float* b   = (const float*)d_in[3];
    float* out       = (float*)d_out;           // fp32 output

    const int E = in_sizes[1] / 2;              // 640000

    char* ws = (char*)d_ws;
    // layout: deg 160000 | dinv 160000 | flag 256 | offs 160000 | cursor 160000
    //         | bsum 1024 | bscan 1024 | csr_src 2560000 | xw 20480000
    int*   deg     = (int*)(ws);
    float* dinv    = (float*)(ws + 160000);
    int*   flag    = (int*)(ws + 320000);
    int*   offs    = (int*)(ws + 320256);
    int*   cursor  = (int*)(ws + 480256);
    int*   bsum    = (int*)(ws + 640256);
    int*   bscan   = (int*)(ws + 641280);
    int*   csr_src = (int*)(ws + 642304);
    float* xw      = (float*)(ws + 3202304);

    detinit_r7<<<(N_NODES + 255) / 256, 256, 0, stream>>>((const int*)edge, flag, deg);
    deg_r7<<<(E + 255) / 256, 256, 0, stream>>>(edge, deg, E, flag);
    partial_r7<<<SCAN_BLOCKS, 256, 0, stream>>>(deg, bsum);
    scanblk_r7<<<1, 256, 0, stream>>>(bsum, bscan);
    offs_r7<<<SCAN_BLOCKS, 256, 0, stream>>>(deg, bscan, offs, cursor, dinv);
    fill_r7<<<(E + 255) / 256, 256, 0, stream>>>(edge, cursor, csr_src, E, flag);
    gemm_r7<<<N_NODES / ROWS, 256, 0, stream>>>(x, W, xw);
    gather_r7<<<N_NODES / 4, 256, 0, stream>>>(csr_src, offs, deg, dinv, xw, b, out);
}

// Round 8
// 223.902 us; speedup vs baseline: 2.7040x; 1.1761x over previous
//
#include <hip/hip_runtime.h>

#define N_NODES 40000
#define IN_DIM 256
#define OUT_DIM 128
#define SCAN_BLOCKS ((N_NODES + 255) / 256)   // 157

typedef __bf16 bf16x8 __attribute__((ext_vector_type(8)));
typedef float floatx4 __attribute__((ext_vector_type(4)));

__device__ __forceinline__ int clamp_idx(int v) {
    unsigned u = (unsigned)v;
    return (u < (unsigned)N_NODES) ? v : 0;
}

__device__ __forceinline__ int get_idx(const void* p, long long i, int is64) {
    if (is64) return clamp_idx((int)((const long long*)p)[i]);
    return clamp_idx(((const int*)p)[i]);
}

// ---- fused: parallel dtype detect (block 0) + deg=1 init (all blocks) ----
__global__ void detinit_r8(const int* __restrict__ edge32, int* __restrict__ flag,
                           int* __restrict__ deg) {
    int i = blockIdx.x * blockDim.x + threadIdx.x;
    if (i < N_NODES) deg[i] = 1;
    if (blockIdx.x == 0) {
        __shared__ int nzs;
        if (threadIdx.x == 0) nzs = 0;
        __syncthreads();
        int nz = 0;
        for (int k = threadIdx.x; k < 1000; k += 256) nz |= (edge32[2 * k + 1] != 0);
        if (nz) atomicOr(&nzs, 1);
        __syncthreads();
        if (threadIdx.x == 0) *flag = nzs ? 0 : 1;   // 1 => int64
    }
}

// ---------------- degree count over dst ----------------
__global__ void deg_r8(const void* __restrict__ edge, int* __restrict__ deg, int E,
                       const int* __restrict__ flag) {
    int is64 = *flag;
    int e = blockIdx.x * blockDim.x + threadIdx.x;
    if (e < E) atomicAdd(&deg[get_idx(edge, (long long)E + e, is64)], 1);
}

// ---------------- hierarchical scan, stage 1: per-block sums ----------------
__global__ void partial_r8(const int* __restrict__ deg, int* __restrict__ bsum) {
    __shared__ int sh[256];
    int t = threadIdx.x;
    int i = blockIdx.x * 256 + t;
    int v = (i < N_NODES) ? (deg[i] - 1) : 0;
    sh[t] = v;
    __syncthreads();
    for (int off = 128; off > 0; off >>= 1) {
        if (t < off) sh[t] += sh[t + off];
        __syncthreads();
    }
    if (t == 0) bsum[blockIdx.x] = sh[0];
}

// ---------------- stage 2: exclusive scan of block sums (1 block) ----------------
__global__ void scanblk_r8(const int* __restrict__ bsum, int* __restrict__ bscan) {
    __shared__ int sh[256];
    int t = threadIdx.x;
    int v = (t < SCAN_BLOCKS) ? bsum[t] : 0;
    sh[t] = v;
    __syncthreads();
    for (int off = 1; off < 256; off <<= 1) {
        int u = (t >= off) ? sh[t - off] : 0;
        __syncthreads();
        sh[t] += u;
        __syncthreads();
    }
    if (t < SCAN_BLOCKS) bscan[t] = sh[t] - v;   // exclusive
}

// ---- stage 3: within-block exclusive scan + base; fused dinv ----
__global__ void offs_r8(const int* __restrict__ deg, const int* __restrict__ bscan,
                        int* __restrict__ offs, int* __restrict__ cursor,
                        float* __restrict__ dinv) {
    __shared__ int sh[256];
    int t = threadIdx.x;
    int i = blockIdx.x * 256 + t;
    int dg = (i < N_NODES) ? deg[i] : 1;
    if (i < N_NODES) dinv[i] = rsqrtf((float)dg);
    int v = dg - 1;
    sh[t] = v;
    __syncthreads();
    for (int off = 1; off < 256; off <<= 1) {
        int u = (t >= off) ? sh[t - off] : 0;
        __syncthreads();
        sh[t] += u;
        __syncthreads();
    }
    if (i < N_NODES) {
        int o = bscan[blockIdx.x] + sh[t] - v;
        offs[i] = o;
        cursor[i] = o;
    }
}

// ---------------- CSR fill: bucket src by dst ----------------
__global__ void fill_r8(const void* __restrict__ edge, int* __restrict__ cursor,
                        int* __restrict__ csr_src, int E, const int* __restrict__ flag) {
    int is64 = *flag;
    int e = blockIdx.x * blockDim.x + threadIdx.x;
    if (e >= E) return;
    int s = get_idx(edge, e, is64);
    int d = get_idx(edge, (long long)E + e, is64);
    int pos = atomicAdd(&cursor[d], 1);
    csr_src[pos] = s;
}

// ---- W -> bf16, pre-swizzled into B-fragment order ----
// frag element: lane L, j -> B[k][n], k = kc*32 + (L>>4)*8 + j, n = ct*16 + (L&15)
// memory index: ((kc*8 + ct)*64 + L)*8 + j
__global__ void wconv_r8(const float* __restrict__ W, __bf16* __restrict__ wswz) {
    int i = blockIdx.x * 256 + threadIdx.x;     // 0..32767
    int j    = i & 7;
    int lane = (i >> 3) & 63;
    int tile = i >> 9;                          // kc*8+ct
    int ct = tile & 7, kc = tile >> 3;
    int k = kc * 32 + (lane >> 4) * 8 + j;
    int n = ct * 16 + (lane & 15);
    wswz[i] = (__bf16)W[k * OUT_DIM + n];
}

// ---- MFMA GEMM: xw = x @ W. 625 blocks x 4 waves; wave = 16 rows x 128 cols ----
// A-frag: A[m=lane&15][k=quad*8+j] built from global fp32 x, converted in-register.
// B-frag: coalesced 16B loads from pre-swizzled bf16 W (L2-hot, 64 KB).
// C/D: col = lane&15, row = quad*4 + reg.
__global__ __launch_bounds__(256) void gemm_r8(const float* __restrict__ x,
                                               const __bf16* __restrict__ wswz,
                                               float* __restrict__ xw) {
    int t = threadIdx.x;
    int wave = t >> 6, lane = t & 63;
    int quad = lane >> 4, m16 = lane & 15;
    int m = blockIdx.x * 64 + wave * 16 + m16;
    const float* xrow = x + (long long)m * IN_DIM;
    const bf16x8* wp = (const bf16x8*)wswz;

    floatx4 acc[8];
#pragma unroll
    for (int ct = 0; ct < 8; ++ct) acc[ct] = (floatx4){0.f, 0.f, 0.f, 0.f};

#pragma unroll
    for (int kc = 0; kc < 8; ++kc) {
        int k0 = kc * 32 + quad * 8;
        float4 xa = *(const float4*)(xrow + k0);
        float4 xb = *(const float4*)(xrow + k0 + 4);
        bf16x8 af;
        af[0] = (__bf16)xa.x; af[1] = (__bf16)xa.y;
        af[2] = (__bf16)xa.z; af[3] = (__bf16)xa.w;
        af[4] = (__bf16)xb.x; af[5] = (__bf16)xb.y;
        af[6] = (__bf16)xb.z; af[7] = (__bf16)xb.w;
#pragma unroll
        for (int ct = 0; ct < 8; ++ct) {
            bf16x8 bf = wp[(kc * 8 + ct) * 64 + lane];
            acc[ct] = __builtin_amdgcn_mfma_f32_16x16x32_bf16(af, bf, acc[ct], 0, 0, 0);
        }
    }

    int rbase = blockIdx.x * 64 + wave * 16 + quad * 4;
#pragma unroll
    for (int ct = 0; ct < 8; ++ct) {
        int col = ct * 16 + m16;
#pragma unroll
        for (int r = 0; r < 4; ++r)
            xw[(long long)(rbase + r) * OUT_DIM + col] = acc[ct][r];
    }
}

// ------- gather: one wave per node, chunked coalesced idx load + shfl ------
__global__ void gather_r8(const int* __restrict__ csr_src, const int* __restrict__ offs,
                          const int* __restrict__ deg, const float* __restrict__ dinv,
                          const float* __restrict__ xw, const float* __restrict__ b,
                          float* __restrict__ out) {
    int node = blockIdx.x * 4 + (threadIdx.x >> 6);
    int lane = threadIdx.x & 63;
    if (node >= N_NODES) return;
    float dd = dinv[node];
    float a0 = dd * dd * xw[node * OUT_DIM + lane];
    float a1 = dd * dd * xw[node * OUT_DIM + 64 + lane];
    int beg = offs[node];
    int cnt = deg[node] - 1;
    for (int c0 = 0; c0 < cnt; c0 += 64) {
        int rem = cnt - c0;
        int take = rem < 64 ? rem : 64;
        int s_l = 0; float nrm_l = 0.0f;
        if (lane < take) {
            s_l = csr_src[beg + c0 + lane];     // coalesced
            nrm_l = dd * dinv[s_l];
        }
        int j = 0;
        for (; j + 4 <= take; j += 4) {
            int   s0 = __shfl(s_l, j),     s1 = __shfl(s_l, j + 1);
            int   s2 = __shfl(s_l, j + 2), s3 = __shfl(s_l, j + 3);
            float n0 = __shfl(nrm_l, j),     n1 = __shfl(nrm_l, j + 1);
            float n2 = __shfl(nrm_l, j + 2), n3 = __shfl(nrm_l, j + 3);
            float x00 = xw[s0 * OUT_DIM + lane], x01 = xw[s0 * OUT_DIM + 64 + lane];
            float x10 = xw[s1 * OUT_DIM + lane], x11 = xw[s1 * OUT_DIM + 64 + lane];
            float x20 = xw[s2 * OUT_DIM + lane], x21 = xw[s2 * OUT_DIM + 64 + lane];
            float x30 = xw[s3 * OUT_DIM + lane], x31 = xw[s3 * OUT_DIM + 64 + lane];
            a0 += n0 * x00; a1 += n0 * x01;
            a0 += n1 * x10; a1 += n1 * x11;
            a0 += n2 * x20; a1 += n2 * x21;
            a0 += n3 * x30; a1 += n3 * x31;
        }
        for (; j < take; ++j) {
            int   s = __shfl(s_l, j);
            float n = __shfl(nrm_l, j);
            a0 += n * xw[s * OUT_DIM + lane];
            a1 += n * xw[s * OUT_DIM + 64 + lane];
        }
    }
    out[node * OUT_DIM + lane]      = fmaxf(a0 + b[lane], 0.0f);
    out[node * OUT_DIM + 64 + lane] = fmaxf(a1 + b[64 + lane], 0.0f);
}

extern "C" void kernel_launch(void* const* d_in, const int* in_sizes, int n_in,
                              void* d_out, int out_size, void* d_ws, size_t ws_size,
                              hipStream_t stream) {
    const float* x   = (const float*)d_in[0];
    const void* edge = d_in[1];                 // int32 or int64, detected on device
    const float* W   = (const float*)d_in[2];
    const float* b   = (const float*)d_in[3];
    float* out       = (float*)d_out;           // fp32 output

    const int E = in_sizes[1] / 2;              // 640000

    char* ws = (char*)d_ws;
    // layout: deg 160000 | dinv 160000 | flag 256 | offs 160000 | cursor 160000
    //         | bsum 1024 | bscan 1024 | wswz 65536 | csr_src 2560000 | xw 20480000
    int*    deg     = (int*)(ws);
    float*  dinv    = (float*)(ws + 160000);
    int*    flag    = (int*)(ws + 320000);
    int*    offs    = (int*)(ws + 320256);
    int*    cursor  = (int*)(ws + 480256);
    int*    bsum    = (int*)(ws + 640256);
    int*    bscan   = (int*)(ws + 641280);
    __bf16* wswz    = (__bf16*)(ws + 642304);
    int*    csr_src = (int*)(ws + 707840);
    float*  xw      = (float*)(ws + 3267840);

    detinit_r8<<<(N_NODES + 255) / 256, 256, 0, stream>>>((const int*)edge, flag, deg);
    deg_r8<<<(E + 255) / 256, 256, 0, stream>>>(edge, deg, E, flag);
    partial_r8<<<SCAN_BLOCKS, 256, 0, stream>>>(deg, bsum);
    scanblk_r8<<<1, 256, 0, stream>>>(bsum, bscan);
    offs_r8<<<SCAN_BLOCKS, 256, 0, stream>>>(deg, bscan, offs, cursor, dinv);
    fill_r8<<<(E + 255) / 256, 256, 0, stream>>>(edge, cursor, csr_src, E, flag);
    wconv_r8<<<128, 256, 0, stream>>>(W, wswz);
    gemm_r8<<<N_NODES / 64, 256, 0, stream>>>(x, wswz, xw);
    gather_r8<<<N_NODES / 4, 256, 0, stream>>>(csr_src, offs, deg, dinv, xw, b, out);
}